// Round 4
// baseline (200.237 us; speedup 1.0000x reference)
//
#include <hip/hip_runtime.h>

#define BB 2
#define NN 2048
#define CQc 256
#define CHc 256
#define HHc 8
#define DDc 32

typedef __bf16 bf16_t;
typedef bf16_t bf16x8 __attribute__((ext_vector_type(8)));
typedef float f32x4 __attribute__((ext_vector_type(4)));

static __device__ __forceinline__ unsigned short f2bf(float f) {
  union { float f; unsigned u; } a; a.f = f;
  unsigned r = a.u + 0x7FFFu + ((a.u >> 16) & 1u);
  return (unsigned short)(r >> 16);
}

static __device__ __forceinline__ bf16x8 ldb8(const unsigned short* p) {
  return *reinterpret_cast<const bf16x8*>(p);
}

// ---------------- kernel 0: weights -> bf16, transposed [n][k] ----------------
__global__ void prep_w(const float* __restrict__ Wq, const float* __restrict__ Wk,
                       const float* __restrict__ Wv, const float* __restrict__ Wg,
                       const float* __restrict__ Wo, unsigned short* __restrict__ wt) {
  int gid = blockIdx.x * 256 + threadIdx.x;  // 0 .. 5*65536-1
  int w = gid >> 16, r = gid & 65535;
  int n = r >> 8, k = r & 255;
  const float* W = (w == 0) ? Wq : (w == 1) ? Wk : (w == 2) ? Wv : (w == 3) ? Wg : Wo;
  wt[gid] = f2bf(W[k * 256 + n]);
}

// ---------------- kernel 1: QKV + gate projections ----------------
__global__ __launch_bounds__(256) void proj_k(
    const float* __restrict__ X, const float* __restrict__ bq,
    const float* __restrict__ bg, const float* __restrict__ gbias,
    const unsigned short* __restrict__ wt,
    unsigned short* __restrict__ q_ws, unsigned short* __restrict__ k_ws,
    unsigned short* __restrict__ vt_ws, float* __restrict__ gate_ws) {
  const int tid = threadIdx.x;
  const int wave = tid >> 6, l = tid & 63, g = l >> 4, l15 = l & 15;
  const int mrow = blockIdx.x * 64 + wave * 16 + l15;  // A-fragment row
  const int c0 = blockIdx.y * 64;                      // global col in [0,1024)
  const int widx = c0 >> 8;                            // which weight
  const int nin0 = c0 & 255;                           // col within weight
  const unsigned short* W = wt + widx * 65536;

  f32x4 acc[4];
#pragma unroll
  for (int st = 0; st < 4; ++st) acc[st] = f32x4{0.f, 0.f, 0.f, 0.f};

#pragma unroll
  for (int kk0 = 0; kk0 < 256; kk0 += 32) {
    const float* xp = X + mrow * 256 + kk0 + 8 * g;
    f32x4 x0 = *reinterpret_cast<const f32x4*>(xp);
    f32x4 x1 = *reinterpret_cast<const f32x4*>(xp + 4);
    union { unsigned short u[8]; bf16x8 v; } av;
#pragma unroll
    for (int e = 0; e < 4; ++e) { av.u[e] = f2bf(x0[e]); av.u[4 + e] = f2bf(x1[e]); }
#pragma unroll
    for (int st = 0; st < 4; ++st) {
      bf16x8 bv = ldb8(W + (nin0 + st * 16 + l15) * 256 + kk0 + 8 * g);
      acc[st] = __builtin_amdgcn_mfma_f32_16x16x32_bf16(av.v, bv, acc[st], 0, 0, 0);
    }
  }

  const int mb = blockIdx.x * 64 + wave * 16 + 4 * g;  // D rows = 4g+j
#pragma unroll
  for (int st = 0; st < 4; ++st) {
    const int n = nin0 + st * 16 + l15;
#pragma unroll
    for (int j = 0; j < 4; ++j) {
      const int m = mb + j;
      const int b = m >> 11, t = m & 2047;
      float val = acc[st][j];
      if (widx == 0) {
        int h = n >> 5, d = n & 31;
        q_ws[((b * 8 + h) * 2048 + t) * 32 + d] = f2bf((val + bq[n]) * 0.17677669529663687f);
      } else if (widx == 1) {
        int h = n >> 5, d = n & 31;
        k_ws[((b * 8 + h) * 2048 + t) * 32 + d] = f2bf(val);
      } else if (widx == 2) {
        int h = n >> 5, d = n & 31;
        vt_ws[((b * 8 + h) * 32 + d) * 2048 + t] = f2bf(val);  // V transposed [b,h,d,n]
      } else {
        float z = val + bg[n] + gbias[n];
        gate_ws[m * 256 + n] = 1.0f / (1.0f + __expf(-z));
      }
    }
  }
}

// ---------------- kernel 2: flash attention with additive bias ----------------
// grid: 512 blocks (16 bh * 32 q-tiles), 4 independent waves, 16 q-rows each
__global__ __launch_bounds__(256) void attn_k(
    const unsigned short* __restrict__ q_ws, const unsigned short* __restrict__ k_ws,
    const unsigned short* __restrict__ vt_ws, const float* __restrict__ bias,
    unsigned short* __restrict__ o_ws) {
  __shared__ unsigned short plds[4 * 16 * 72];  // per-wave P buffer, pitch 72 bf16
  const int tid = threadIdx.x;
  const int wave = tid >> 6, l = tid & 63, g = l >> 4, l15 = l & 15;
  const int bh = blockIdx.x >> 5, qt = blockIdx.x & 31;
  const int qr0 = qt * 64 + wave * 16;
  const int kvbase = bh * 2048;
  unsigned short* pw = plds + wave * (16 * 72);

  const bf16x8 qa = ldb8(q_ws + (size_t)(kvbase + qr0 + l15) * 32 + 8 * g);
  const float* bias_b = bias + (size_t)bh * 2048 * 2048 + (size_t)qr0 * 2048;

  float mr[4], lr[4];
  f32x4 oacc[2];
#pragma unroll
  for (int j = 0; j < 4; ++j) { mr[j] = -1e30f; lr[j] = 0.0f; }
  oacc[0] = f32x4{0.f, 0.f, 0.f, 0.f};
  oacc[1] = f32x4{0.f, 0.f, 0.f, 0.f};
  const f32x4 zf = f32x4{0.f, 0.f, 0.f, 0.f};

  for (int kt = 0; kt < 32; ++kt) {
    const int k0 = kt * 64;
    // V fragments (independent of S — issue early)
    bf16x8 vb[2][2];
#pragma unroll
    for (int dst = 0; dst < 2; ++dst)
#pragma unroll
      for (int kc = 0; kc < 2; ++kc)
        vb[dst][kc] = ldb8(vt_ws + (size_t)(bh * 32 + dst * 16 + l15) * 2048 + k0 + kc * 32 + 8 * g);
    // bias: element (q=4g+j, k=st*16+l15) — matches MFMA D layout, 64B segments
    float bvals[4][4];
#pragma unroll
    for (int j = 0; j < 4; ++j)
#pragma unroll
      for (int st = 0; st < 4; ++st)
        bvals[st][j] = bias_b[(4 * g + j) * 2048 + k0 + st * 16 + l15];
    // S = Q K^T
    f32x4 s[4];
#pragma unroll
    for (int st = 0; st < 4; ++st) {
      bf16x8 kb = ldb8(k_ws + (size_t)(kvbase + k0 + st * 16 + l15) * 32 + 8 * g);
      s[st] = __builtin_amdgcn_mfma_f32_16x16x32_bf16(qa, kb, zf, 0, 0, 0);
    }
    float sv[4][4];
#pragma unroll
    for (int st = 0; st < 4; ++st)
#pragma unroll
      for (int j = 0; j < 4; ++j) sv[st][j] = s[st][j] + bvals[st][j];

    // online softmax per row (row = 4g+j); reduce over st in-lane + 16 lanes
    float pf[4][4];
#pragma unroll
    for (int j = 0; j < 4; ++j) {
      float mx = fmaxf(fmaxf(sv[0][j], sv[1][j]), fmaxf(sv[2][j], sv[3][j]));
      mx = fmaxf(mx, __shfl_xor(mx, 1));
      mx = fmaxf(mx, __shfl_xor(mx, 2));
      mx = fmaxf(mx, __shfl_xor(mx, 4));
      mx = fmaxf(mx, __shfl_xor(mx, 8));
      const float mn = fmaxf(mr[j], mx);
      const float sc = __expf(mr[j] - mn);
      mr[j] = mn;
      float rs = 0.f;
#pragma unroll
      for (int st = 0; st < 4; ++st) { pf[st][j] = __expf(sv[st][j] - mn); rs += pf[st][j]; }
      rs += __shfl_xor(rs, 1);
      rs += __shfl_xor(rs, 2);
      rs += __shfl_xor(rs, 4);
      rs += __shfl_xor(rs, 8);
      lr[j] = lr[j] * sc + rs;
      oacc[0][j] *= sc;
      oacc[1][j] *= sc;
    }
    // P -> LDS (transpose to A-fragment layout); per-wave buffer, DS ops in-order
#pragma unroll
    for (int st = 0; st < 4; ++st)
#pragma unroll
      for (int j = 0; j < 4; ++j)
        pw[(4 * g + j) * 72 + st * 16 + l15] = f2bf(pf[st][j]);
    // PV
#pragma unroll
    for (int kc = 0; kc < 2; ++kc) {
      bf16x8 pa = ldb8(pw + l15 * 72 + kc * 32 + 8 * g);
      oacc[0] = __builtin_amdgcn_mfma_f32_16x16x32_bf16(pa, vb[0][kc], oacc[0], 0, 0, 0);
      oacc[1] = __builtin_amdgcn_mfma_f32_16x16x32_bf16(pa, vb[1][kc], oacc[1], 0, 0, 0);
    }
  }

  const int b = bh >> 3, h = bh & 7;
#pragma unroll
  for (int dst = 0; dst < 2; ++dst)
#pragma unroll
    for (int j = 0; j < 4; ++j) {
      const int q = qr0 + 4 * g + j;
      const float val = oacc[dst][j] / lr[j];
      o_ws[((size_t)b * 2048 + q) * 256 + h * 32 + dst * 16 + l15] = f2bf(val);
    }
}

// ---------------- kernel 3: out = gate * (o @ Wout + bout) ----------------
__global__ __launch_bounds__(256) void outp_k(
    const unsigned short* __restrict__ o_ws, const unsigned short* __restrict__ wot,
    const float* __restrict__ bout, const float* __restrict__ gate_ws,
    float* __restrict__ out) {
  const int tid = threadIdx.x;
  const int wave = tid >> 6, l = tid & 63, g = l >> 4, l15 = l & 15;
  const int m0 = blockIdx.x * 64 + wave * 16;
  const int c0 = blockIdx.y * 64;
  f32x4 acc[4];
#pragma unroll
  for (int st = 0; st < 4; ++st) acc[st] = f32x4{0.f, 0.f, 0.f, 0.f};
#pragma unroll
  for (int kk0 = 0; kk0 < 256; kk0 += 32) {
    bf16x8 a = ldb8(o_ws + (m0 + l15) * 256 + kk0 + 8 * g);
#pragma unroll
    for (int st = 0; st < 4; ++st) {
      bf16x8 bv = ldb8(wot + (c0 + st * 16 + l15) * 256 + kk0 + 8 * g);
      acc[st] = __builtin_amdgcn_mfma_f32_16x16x32_bf16(a, bv, acc[st], 0, 0, 0);
    }
  }
  const int mb = m0 + 4 * g;
#pragma unroll
  for (int st = 0; st < 4; ++st) {
    const int n = c0 + st * 16 + l15;
#pragma unroll
    for (int j = 0; j < 4; ++j) {
      const int m = mb + j;
      const float val = acc[st][j] + bout[n];
      out[m * 256 + n] = gate_ws[m * 256 + n] * val;
    }
  }
}

extern "C" void kernel_launch(void* const* d_in, const int* in_sizes, int n_in,
                              void* d_out, int out_size, void* d_ws, size_t ws_size,
                              hipStream_t stream) {
  const float* q_x   = (const float*)d_in[0];
  const float* bias  = (const float*)d_in[1];
  const float* Wq    = (const float*)d_in[2];
  const float* bq    = (const float*)d_in[3];
  const float* Wk    = (const float*)d_in[4];
  const float* Wv    = (const float*)d_in[5];
  const float* Wout  = (const float*)d_in[6];
  const float* bout  = (const float*)d_in[7];
  const float* Wg    = (const float*)d_in[8];
  const float* bg    = (const float*)d_in[9];
  const float* gbias = (const float*)d_in[10];
  float* out = (float*)d_out;

  char* ws = (char*)d_ws;
  unsigned short* wt    = (unsigned short*)(ws);                        // 655,360 B
  unsigned short* q_ws  = (unsigned short*)(ws + 655360);               // 2 MB
  unsigned short* k_ws  = (unsigned short*)(ws + 655360 + 2097152);     // 2 MB
  unsigned short* vt_ws = (unsigned short*)(ws + 655360 + 2 * 2097152); // 2 MB
  unsigned short* o_ws  = (unsigned short*)(ws + 655360 + 3 * 2097152); // 2 MB
  float* gate_ws        = (float*)(ws + 655360 + 4 * 2097152);          // 4 MB
  unsigned short* o_ws2 = (unsigned short*)(ws + 655360 + 4 * 2097152 + 4194304);  // 2 MB (dead — timing probe)

  prep_w<<<1280, 256, 0, stream>>>(Wq, Wk, Wv, Wg, Wout, wt);
  proj_k<<<dim3(64, 16), 256, 0, stream>>>(q_x, bq, bg, gbias, wt, q_ws, k_ws, vt_ws, gate_ws);
  attn_k<<<512, 256, 0, stream>>>(q_ws, k_ws, vt_ws, bias, o_ws);
  // Timing probe: identical second attention pass into a dead buffer.
  // dur_us - 124.7 == attn_k's duration (bias re-streamed from HBM; LLC < bias size).
  attn_k<<<512, 256, 0, stream>>>(q_ws, k_ws, vt_ws, bias, o_ws2);
  outp_k<<<dim3(64, 4), 256, 0, stream>>>(o_ws, wt + 4 * 65536, bout, gate_ws, out);
}

// Round 5
// 118.613 us; speedup vs baseline: 1.6881x; 1.6881x over previous
//
#include <hip/hip_runtime.h>

#define BB 2
#define NN 2048
#define CQc 256
#define CHc 256
#define HHc 8
#define DDc 32

typedef __bf16 bf16_t;
typedef bf16_t bf16x8 __attribute__((ext_vector_type(8)));
typedef float f32x4 __attribute__((ext_vector_type(4)));

#define LOG2E 1.4426950408889634f

static __device__ __forceinline__ unsigned short f2bf(float f) {
  union { float f; unsigned u; } a; a.f = f;
  unsigned r = a.u + 0x7FFFu + ((a.u >> 16) & 1u);
  return (unsigned short)(r >> 16);
}

static __device__ __forceinline__ bf16x8 ldb8(const unsigned short* p) {
  return *reinterpret_cast<const bf16x8*>(p);
}

// ---------------- kernel 0: weights -> bf16, transposed [n][k] ----------------
__global__ void prep_w(const float* __restrict__ Wq, const float* __restrict__ Wk,
                       const float* __restrict__ Wv, const float* __restrict__ Wg,
                       const float* __restrict__ Wo, unsigned short* __restrict__ wt) {
  int gid = blockIdx.x * 256 + threadIdx.x;  // 0 .. 5*65536-1
  int w = gid >> 16, r = gid & 65535;
  int n = r >> 8, k = r & 255;
  const float* W = (w == 0) ? Wq : (w == 1) ? Wk : (w == 2) ? Wv : (w == 3) ? Wg : Wo;
  wt[gid] = f2bf(W[k * 256 + n]);
}

// ---------------- kernel 1: QKV + gate projections ----------------
// q is pre-scaled by (1/sqrt(D)) * log2(e) so attention softmax can use exp2.
__global__ __launch_bounds__(256) void proj_k(
    const float* __restrict__ X, const float* __restrict__ bq,
    const float* __restrict__ bg, const float* __restrict__ gbias,
    const unsigned short* __restrict__ wt,
    unsigned short* __restrict__ q_ws, unsigned short* __restrict__ k_ws,
    unsigned short* __restrict__ vt_ws, float* __restrict__ gate_ws) {
  const int tid = threadIdx.x;
  const int wave = tid >> 6, l = tid & 63, g = l >> 4, l15 = l & 15;
  const int mrow = blockIdx.x * 64 + wave * 16 + l15;  // A-fragment row
  const int c0 = blockIdx.y * 64;                      // global col in [0,1024)
  const int widx = c0 >> 8;                            // which weight
  const int nin0 = c0 & 255;                           // col within weight
  const unsigned short* W = wt + widx * 65536;

  f32x4 acc[4];
#pragma unroll
  for (int st = 0; st < 4; ++st) acc[st] = f32x4{0.f, 0.f, 0.f, 0.f};

#pragma unroll
  for (int kk0 = 0; kk0 < 256; kk0 += 32) {
    const float* xp = X + mrow * 256 + kk0 + 8 * g;
    f32x4 x0 = *reinterpret_cast<const f32x4*>(xp);
    f32x4 x1 = *reinterpret_cast<const f32x4*>(xp + 4);
    union { unsigned short u[8]; bf16x8 v; } av;
#pragma unroll
    for (int e = 0; e < 4; ++e) { av.u[e] = f2bf(x0[e]); av.u[4 + e] = f2bf(x1[e]); }
#pragma unroll
    for (int st = 0; st < 4; ++st) {
      bf16x8 bv = ldb8(W + (nin0 + st * 16 + l15) * 256 + kk0 + 8 * g);
      acc[st] = __builtin_amdgcn_mfma_f32_16x16x32_bf16(av.v, bv, acc[st], 0, 0, 0);
    }
  }

  const int mb = blockIdx.x * 64 + wave * 16 + 4 * g;  // D rows = 4g+j
#pragma unroll
  for (int st = 0; st < 4; ++st) {
    const int n = nin0 + st * 16 + l15;
#pragma unroll
    for (int j = 0; j < 4; ++j) {
      const int m = mb + j;
      const int b = m >> 11, t = m & 2047;
      float val = acc[st][j];
      if (widx == 0) {
        int h = n >> 5, d = n & 31;
        q_ws[((b * 8 + h) * 2048 + t) * 32 + d] =
            f2bf((val + bq[n]) * (0.17677669529663687f * LOG2E));
      } else if (widx == 1) {
        int h = n >> 5, d = n & 31;
        k_ws[((b * 8 + h) * 2048 + t) * 32 + d] = f2bf(val);
      } else if (widx == 2) {
        int h = n >> 5, d = n & 31;
        vt_ws[((b * 8 + h) * 32 + d) * 2048 + t] = f2bf(val);  // V transposed [b,h,d,n]
      } else {
        float z = val + bg[n] + gbias[n];
        gate_ws[m * 256 + n] = 1.0f / (1.0f + __expf(-z));
      }
    }
  }
}

// ---------------- kernel 2: flash attention, LDS-staged bias, depth-2 pipeline ----
// grid: 512 blocks (16 bh * 32 q-tiles), 4 independent waves (no barriers), 16 q-rows each.
// Bias tiles [16 rows x 64 cols] fp32 staged into per-wave LDS via global_load_lds
// (16B/lane), triple-buffered; stage(kt+2) issued during tile kt. Completion of
// stage(kt) enforced by counted s_waitcnt vmcnt(4) (in-order retirement) +
// sched_barrier(0) so the ds_reads can't hoist above the wait.
__global__ __launch_bounds__(256) void attn_k(
    const unsigned short* __restrict__ q_ws, const unsigned short* __restrict__ k_ws,
    const unsigned short* __restrict__ vt_ws, const float* __restrict__ bias,
    unsigned short* __restrict__ o_ws) {
  __shared__ float sbias[4 * 3 * 1024];         // [wave][3 bufs][16*64] = 48 KB
  __shared__ unsigned short plds[4 * 16 * 72];  // per-wave P buffer, pitch 72 bf16
  const int tid = threadIdx.x;
  const int wave = tid >> 6, l = tid & 63, g = l >> 4, l15 = l & 15;
  const int bh = blockIdx.x >> 5, qt = blockIdx.x & 31;
  const int qr0 = qt * 64 + wave * 16;
  const int kvbase = bh * 2048;
  unsigned short* pw = plds + wave * (16 * 72);
  float* sb = sbias + wave * 3072;

  const bf16x8 qa = ldb8(q_ws + (size_t)(kvbase + qr0 + l15) * 32 + 8 * g);
  const unsigned short* kbase = k_ws + (size_t)kvbase * 32 + 8 * g + l15 * 32;
  const unsigned short* vbase = vt_ws + (size_t)(bh * 32 + l15) * 2048 + 8 * g;
  // per-lane staging source: lane l covers row (l>>4) of each 4-row group, 16B at col (l&15)*4
  const float* bsrc = bias + ((size_t)bh << 22) + (size_t)(qr0 + (l >> 4)) * 2048 + (l & 15) * 4;

  // stage tile with key-offset k0 into LDS buffer bidx (4 x 1KB instrs)
  auto stage = [&](int bidx, int k0) {
    float* dst = sb + bidx * 1024;
#pragma unroll
    for (int qq = 0; qq < 4; ++qq)
      __builtin_amdgcn_global_load_lds(
          (const __attribute__((address_space(1))) void*)(bsrc + (size_t)qq * 8192 + k0),
          (__attribute__((address_space(3))) void*)(dst + qq * 256), 16, 0, 0);
  };

  float mr[4], lr[4];
  f32x4 oacc[2];
#pragma unroll
  for (int j = 0; j < 4; ++j) { mr[j] = -1e30f; lr[j] = 0.0f; }
  oacc[0] = f32x4{0.f, 0.f, 0.f, 0.f};
  oacc[1] = f32x4{0.f, 0.f, 0.f, 0.f};

  stage(0, 0);
  stage(1, 64);
  int cb = 0;  // buffer holding tile kt
#pragma unroll 1
  for (int kt = 0; kt < 32; ++kt) {
    const int k0 = kt * 64;
    // wait for stage(kt); stage(kt+1)'s 4 loads may stay in flight
    if (kt < 31) {
      asm volatile("s_waitcnt vmcnt(4)" ::: "memory");
    } else {
      asm volatile("s_waitcnt vmcnt(0)" ::: "memory");
    }
    __builtin_amdgcn_sched_barrier(0);
    // bias fragments (C-operand layout) from LDS buffer cb
    f32x4 cfr[4];
    const float* sbc = sb + cb * 1024 + l15;
#pragma unroll
    for (int st = 0; st < 4; ++st)
#pragma unroll
      for (int j = 0; j < 4; ++j)
        cfr[st][j] = sbc[(4 * g + j) * 64 + st * 16] * LOG2E;

    // K/V fragment loads for this tile (issued before next staging)
    bf16x8 kb[4];
#pragma unroll
    for (int st = 0; st < 4; ++st) kb[st] = ldb8(kbase + (size_t)(k0 + st * 16) * 32);
    bf16x8 vb[2][2];
#pragma unroll
    for (int dst = 0; dst < 2; ++dst)
#pragma unroll
      for (int kc = 0; kc < 2; ++kc)
        vb[dst][kc] = ldb8(vbase + (size_t)dst * 16 * 2048 + k0 + kc * 32);

    // issue stage(kt+2) into the buffer freed at kt-1
    int nb = cb + 2; if (nb >= 3) nb -= 3;
    if (kt < 30) stage(nb, k0 + 128);

    // S = QK^T + bias (bias as MFMA C-operand), base-2 domain
    f32x4 s[4];
#pragma unroll
    for (int st = 0; st < 4; ++st)
      s[st] = __builtin_amdgcn_mfma_f32_16x16x32_bf16(qa, kb[st], cfr[st], 0, 0, 0);

    // online softmax per row (row = 4g+j)
#pragma unroll
    for (int j = 0; j < 4; ++j) {
      float mx = fmaxf(fmaxf(s[0][j], s[1][j]), fmaxf(s[2][j], s[3][j]));
      mx = fmaxf(mx, __shfl_xor(mx, 1));
      mx = fmaxf(mx, __shfl_xor(mx, 2));
      mx = fmaxf(mx, __shfl_xor(mx, 4));
      mx = fmaxf(mx, __shfl_xor(mx, 8));
      const float mn = fmaxf(mr[j], mx);
      const float sc = __builtin_amdgcn_exp2f(mr[j] - mn);
      mr[j] = mn;
      float rs = 0.f;
#pragma unroll
      for (int st = 0; st < 4; ++st) {
        float e = __builtin_amdgcn_exp2f(s[st][j] - mn);
        s[st][j] = e;
        rs += e;
      }
      rs += __shfl_xor(rs, 1);
      rs += __shfl_xor(rs, 2);
      rs += __shfl_xor(rs, 4);
      rs += __shfl_xor(rs, 8);
      lr[j] = lr[j] * sc + rs;
      oacc[0][j] *= sc;
      oacc[1][j] *= sc;
    }
    // P -> LDS (transpose to A-fragment layout); per-wave buffer, DS in-order
#pragma unroll
    for (int st = 0; st < 4; ++st)
#pragma unroll
      for (int j = 0; j < 4; ++j)
        pw[(4 * g + j) * 72 + st * 16 + l15] = f2bf(s[st][j]);
#pragma unroll
    for (int kc = 0; kc < 2; ++kc) {
      bf16x8 pa = ldb8(pw + l15 * 72 + kc * 32 + 8 * g);
      oacc[0] = __builtin_amdgcn_mfma_f32_16x16x32_bf16(pa, vb[0][kc], oacc[0], 0, 0, 0);
      oacc[1] = __builtin_amdgcn_mfma_f32_16x16x32_bf16(pa, vb[1][kc], oacc[1], 0, 0, 0);
    }
    cb = cb + 1; if (cb >= 3) cb -= 3;
  }

  const int b = bh >> 3, h = bh & 7;
#pragma unroll
  for (int dst = 0; dst < 2; ++dst)
#pragma unroll
    for (int j = 0; j < 4; ++j) {
      const int q = qr0 + 4 * g + j;
      const float val = oacc[dst][j] / lr[j];
      o_ws[((size_t)(b * 2048 + q)) * 256 + h * 32 + dst * 16 + l15] = f2bf(val);
    }
}

// ---------------- kernel 3: out = gate * (o @ Wout + bout) ----------------
__global__ __launch_bounds__(256) void outp_k(
    const unsigned short* __restrict__ o_ws, const unsigned short* __restrict__ wot,
    const float* __restrict__ bout, const float* __restrict__ gate_ws,
    float* __restrict__ out) {
  const int tid = threadIdx.x;
  const int wave = tid >> 6, l = tid & 63, g = l >> 4, l15 = l & 15;
  const int m0 = blockIdx.x * 64 + wave * 16;
  const int c0 = blockIdx.y * 64;
  f32x4 acc[4];
#pragma unroll
  for (int st = 0; st < 4; ++st) acc[st] = f32x4{0.f, 0.f, 0.f, 0.f};
#pragma unroll
  for (int kk0 = 0; kk0 < 256; kk0 += 32) {
    bf16x8 a = ldb8(o_ws + (m0 + l15) * 256 + kk0 + 8 * g);
#pragma unroll
    for (int st = 0; st < 4; ++st) {
      bf16x8 bv = ldb8(wot + (c0 + st * 16 + l15) * 256 + kk0 + 8 * g);
      acc[st] = __builtin_amdgcn_mfma_f32_16x16x32_bf16(a, bv, acc[st], 0, 0, 0);
    }
  }
  const int mb = m0 + 4 * g;
#pragma unroll
  for (int st = 0; st < 4; ++st) {
    const int n = c0 + st * 16 + l15;
#pragma unroll
    for (int j = 0; j < 4; ++j) {
      const int m = mb + j;
      const float val = acc[st][j] + bout[n];
      out[m * 256 + n] = gate_ws[m * 256 + n] * val;
    }
  }
}

extern "C" void kernel_launch(void* const* d_in, const int* in_sizes, int n_in,
                              void* d_out, int out_size, void* d_ws, size_t ws_size,
                              hipStream_t stream) {
  const float* q_x   = (const float*)d_in[0];
  const float* bias  = (const float*)d_in[1];
  const float* Wq    = (const float*)d_in[2];
  const float* bq    = (const float*)d_in[3];
  const float* Wk    = (const float*)d_in[4];
  const float* Wv    = (const float*)d_in[5];
  const float* Wout  = (const float*)d_in[6];
  const float* bout  = (const float*)d_in[7];
  const float* Wg    = (const float*)d_in[8];
  const float* bg    = (const float*)d_in[9];
  const float* gbias = (const float*)d_in[10];
  float* out = (float*)d_out;

  char* ws = (char*)d_ws;
  unsigned short* wt    = (unsigned short*)(ws);                        // 655,360 B
  unsigned short* q_ws  = (unsigned short*)(ws + 655360);               // 2 MB
  unsigned short* k_ws  = (unsigned short*)(ws + 655360 + 2097152);     // 2 MB
  unsigned short* vt_ws = (unsigned short*)(ws + 655360 + 2 * 2097152); // 2 MB
  unsigned short* o_ws  = (unsigned short*)(ws + 655360 + 3 * 2097152); // 2 MB
  float* gate_ws        = (float*)(ws + 655360 + 4 * 2097152);          // 4 MB

  prep_w<<<1280, 256, 0, stream>>>(Wq, Wk, Wv, Wg, Wout, wt);
  proj_k<<<dim3(64, 16), 256, 0, stream>>>(q_x, bq, bg, gbias, wt, q_ws, k_ws, vt_ws, gate_ws);
  attn_k<<<512, 256, 0, stream>>>(q_ws, k_ws, vt_ws, bias, o_ws);
  outp_k<<<dim3(64, 4), 256, 0, stream>>>(o_ws, wt + 4 * 65536, bout, gate_ws, out);
}